// Round 1
// baseline (887.774 us; speedup 1.0000x reference)
//
#include <hip/hip_runtime.h>
#include <math.h>

#define N_NODES 100000
#define N_EDGES 1600000
#define D_FEAT  64

// One wave (64 lanes) per edge; lane k handles feature k.
// src/dst loads are wave-uniform (all lanes same e), feature row read is
// coalesced 256B, atomicAdd scatter is coalesced. Lane 0 bumps deg.
__global__ void scatter_round1(const float* __restrict__ feat,
                               const int* __restrict__ src_idx,
                               const int* __restrict__ dst_idx,
                               float* __restrict__ acc,
                               float* __restrict__ deg) {
    long long tid = (long long)blockIdx.x * blockDim.x + threadIdx.x;
    long long e = tid >> 6;
    int k = (int)(tid & 63);
    if (e >= N_EDGES) return;
    int s = src_idx[e];
    int d = dst_idx[e];
    float v = feat[(long long)s * D_FEAT + k];
    atomicAdd(&acc[(long long)d * D_FEAT + k], v);
    if (k == 0) atomicAdd(&deg[d], 1.0f);
}

// x1 = deg>0 ? acc/deg : 0   (in place)
__global__ void divide_kernel(float* __restrict__ acc,
                              const float* __restrict__ deg) {
    int tid = blockIdx.x * blockDim.x + threadIdx.x;
    if (tid >= N_NODES * D_FEAT) return;
    int node = tid >> 6;
    float dg = deg[node];
    float v = acc[tid];
    acc[tid] = (dg > 0.0f) ? v / dg : 0.0f;
}

// Round 2: scatter x1 into the output buffer (used as accumulator).
__global__ void scatter_round2(const float* __restrict__ x1,
                               const int* __restrict__ src_idx,
                               const int* __restrict__ dst_idx,
                               float* __restrict__ acc2) {
    long long tid = (long long)blockIdx.x * blockDim.x + threadIdx.x;
    long long e = tid >> 6;
    int k = (int)(tid & 63);
    if (e >= N_EDGES) return;
    int s = src_idx[e];
    int d = dst_idx[e];
    float v = x1[(long long)s * D_FEAT + k];
    atomicAdd(&acc2[(long long)d * D_FEAT + k], v);
}

// One wave per node: x2 = acc2/deg, cosine blend, write output in place.
__global__ void finalize_kernel(const float* __restrict__ x1,
                                float* __restrict__ out_acc, // acc2 in, result out
                                const float* __restrict__ deg) {
    int node = blockIdx.x * (blockDim.x >> 6) + (threadIdx.x >> 6);
    int k = threadIdx.x & 63;
    if (node >= N_NODES) return;
    float dg = deg[node];
    long long idx = (long long)node * D_FEAT + k;
    float a = x1[idx];                       // x1
    float s2 = out_acc[idx];
    float b = (dg > 0.0f) ? s2 / dg : 0.0f;  // x2

    float dot = a * b;
    float nn1 = a * a;
    float nn2 = b * b;
    #pragma unroll
    for (int off = 32; off > 0; off >>= 1) {
        dot += __shfl_xor(dot, off);
        nn1 += __shfl_xor(nn1, off);
        nn2 += __shfl_xor(nn2, off);
    }
    float denom = fmaxf(sqrtf(nn1) * sqrtf(nn2), 1e-8f);
    float w = dot / denom;
    out_acc[idx] = w * b + (1.0f - w) * a;
}

extern "C" void kernel_launch(void* const* d_in, const int* in_sizes, int n_in,
                              void* d_out, int out_size, void* d_ws, size_t ws_size,
                              hipStream_t stream) {
    const float* feat = (const float*)d_in[0];
    const int*   eidx = (const int*)d_in[1];   // (2, N_EDGES) int
    const int*   src  = eidx;                  // row 0
    const int*   dst  = eidx + N_EDGES;        // row 1

    float* acc1 = (float*)d_ws;                              // N_NODES*64 floats (x1)
    float* deg  = acc1 + (size_t)N_NODES * D_FEAT;           // N_NODES floats
    float* out  = (float*)d_out;                             // acc2, then result

    size_t zero_ws_bytes = ((size_t)N_NODES * D_FEAT + N_NODES) * sizeof(float);
    hipMemsetAsync(d_ws, 0, zero_ws_bytes, stream);
    hipMemsetAsync(d_out, 0, (size_t)out_size * sizeof(float), stream);

    const int BLK = 256;
    long long scatter_threads = (long long)N_EDGES * 64;
    int scatter_blocks = (int)((scatter_threads + BLK - 1) / BLK);

    scatter_round1<<<scatter_blocks, BLK, 0, stream>>>(feat, src, dst, acc1, deg);

    int nelems = N_NODES * D_FEAT;
    divide_kernel<<<(nelems + BLK - 1) / BLK, BLK, 0, stream>>>(acc1, deg);

    scatter_round2<<<scatter_blocks, BLK, 0, stream>>>(acc1, src, dst, out);

    int nodes_per_block = BLK / 64;
    finalize_kernel<<<(N_NODES + nodes_per_block - 1) / nodes_per_block, BLK, 0, stream>>>(
        acc1, out, deg);
}

// Round 2
// 385.581 us; speedup vs baseline: 2.3024x; 2.3024x over previous
//
#include <hip/hip_runtime.h>
#include <math.h>

#define N_NODES 100000
#define N_EDGES 1600000
#define D_FEAT  64
#define SCAN_BLOCK 1024
#define N_SCAN_BLOCKS ((N_NODES + SCAN_BLOCK - 1) / SCAN_BLOCK)  // 98

// ---- CSR build ----------------------------------------------------------

__global__ void histogram_kernel(const int* __restrict__ dst,
                                 int* __restrict__ counts) {
    int e = blockIdx.x * blockDim.x + threadIdx.x;
    if (e < N_EDGES) atomicAdd(&counts[dst[e]], 1);
}

// Per-block exclusive scan of counts -> offsets, block totals -> bsum.
__global__ void scan_block_kernel(const int* __restrict__ counts,
                                  int* __restrict__ offsets,
                                  int* __restrict__ bsum) {
    __shared__ int tmp[SCAN_BLOCK];
    int i = blockIdx.x * SCAN_BLOCK + threadIdx.x;
    int v = (i < N_NODES) ? counts[i] : 0;
    tmp[threadIdx.x] = v;
    __syncthreads();
    for (int off = 1; off < SCAN_BLOCK; off <<= 1) {
        int t = (threadIdx.x >= off) ? tmp[threadIdx.x - off] : 0;
        __syncthreads();
        tmp[threadIdx.x] += t;
        __syncthreads();
    }
    int incl = tmp[threadIdx.x];
    if (i < N_NODES) offsets[i] = incl - v;              // exclusive
    if (threadIdx.x == SCAN_BLOCK - 1) bsum[blockIdx.x] = incl;
}

// Exclusive scan of the 98 block sums (single block).
__global__ void scan_bsum_kernel(int* __restrict__ bsum) {
    __shared__ int tmp[128];
    int i = threadIdx.x;
    int v = (i < N_SCAN_BLOCKS) ? bsum[i] : 0;
    tmp[i] = v;
    __syncthreads();
    for (int off = 1; off < 128; off <<= 1) {
        int t = (i >= off) ? tmp[i - off] : 0;
        __syncthreads();
        tmp[i] += t;
        __syncthreads();
    }
    if (i < N_SCAN_BLOCKS) bsum[i] = tmp[i] - v;         // exclusive
}

// Add block prefix, reset counts (reused as fill cursor), set sentinel.
__global__ void scan_add_kernel(int* __restrict__ offsets,
                                const int* __restrict__ bsum,
                                int* __restrict__ counts) {
    int i = blockIdx.x * SCAN_BLOCK + threadIdx.x;
    if (i < N_NODES) {
        offsets[i] += bsum[blockIdx.x];
        counts[i] = 0;
    }
    if (i == 0) offsets[N_NODES] = N_EDGES;
}

__global__ void fill_csr_kernel(const int* __restrict__ src,
                                const int* __restrict__ dst,
                                const int* __restrict__ offsets,
                                int* __restrict__ cursor,
                                int* __restrict__ csr_src) {
    int e = blockIdx.x * blockDim.x + threadIdx.x;
    if (e >= N_EDGES) return;
    int d = dst[e];
    int pos = offsets[d] + atomicAdd(&cursor[d], 1);
    csr_src[pos] = src[e];
}

// ---- Gather passes ------------------------------------------------------
// One wave per node. Lane layout: group = lane>>4 (edge sub-batch of 4),
// fid = (lane&15)*4 (float4 of the feature row). One global_load_dwordx4
// per iteration fetches 4 source rows x 1KB across the wave.

__global__ void gather1_kernel(const float* __restrict__ feat,
                               const int* __restrict__ offsets,
                               const int* __restrict__ csr_src,
                               float* __restrict__ x1) {
    int node = blockIdx.x * (blockDim.x >> 6) + (threadIdx.x >> 6);
    if (node >= N_NODES) return;
    int lane = threadIdx.x & 63;
    int group = lane >> 4;
    int fid = (lane & 15) * 4;

    int base = offsets[node];
    int deg = offsets[node + 1] - base;

    float4 acc = make_float4(0.f, 0.f, 0.f, 0.f);
    for (int j = 0; j < deg; j += 4) {
        int idx = j + group;
        if (idx < deg) {
            int s = csr_src[base + idx];
            float4 v = *(const float4*)&feat[(long long)s * D_FEAT + fid];
            acc.x += v.x; acc.y += v.y; acc.z += v.z; acc.w += v.w;
        }
    }
    // combine the 4 edge sub-batches (groups) -> all lanes hold full sum
    acc.x += __shfl_xor(acc.x, 16); acc.x += __shfl_xor(acc.x, 32);
    acc.y += __shfl_xor(acc.y, 16); acc.y += __shfl_xor(acc.y, 32);
    acc.z += __shfl_xor(acc.z, 16); acc.z += __shfl_xor(acc.z, 32);
    acc.w += __shfl_xor(acc.w, 16); acc.w += __shfl_xor(acc.w, 32);

    if (group == 0) {
        float inv = (deg > 0) ? 1.0f / (float)deg : 0.0f;
        float4 r = make_float4(acc.x * inv, acc.y * inv, acc.z * inv, acc.w * inv);
        *(float4*)&x1[(long long)node * D_FEAT + fid] = r;
    }
}

// Gather round 2 + fused cosine blend epilogue.
__global__ void gather2_finalize_kernel(const float* __restrict__ x1,
                                        const int* __restrict__ offsets,
                                        const int* __restrict__ csr_src,
                                        float* __restrict__ out) {
    int node = blockIdx.x * (blockDim.x >> 6) + (threadIdx.x >> 6);
    if (node >= N_NODES) return;
    int lane = threadIdx.x & 63;
    int group = lane >> 4;
    int fid = (lane & 15) * 4;

    int base = offsets[node];
    int deg = offsets[node + 1] - base;

    float4 acc = make_float4(0.f, 0.f, 0.f, 0.f);
    for (int j = 0; j < deg; j += 4) {
        int idx = j + group;
        if (idx < deg) {
            int s = csr_src[base + idx];
            float4 v = *(const float4*)&x1[(long long)s * D_FEAT + fid];
            acc.x += v.x; acc.y += v.y; acc.z += v.z; acc.w += v.w;
        }
    }
    acc.x += __shfl_xor(acc.x, 16); acc.x += __shfl_xor(acc.x, 32);
    acc.y += __shfl_xor(acc.y, 16); acc.y += __shfl_xor(acc.y, 32);
    acc.z += __shfl_xor(acc.z, 16); acc.z += __shfl_xor(acc.z, 32);
    acc.w += __shfl_xor(acc.w, 16); acc.w += __shfl_xor(acc.w, 32);

    float inv = (deg > 0) ? 1.0f / (float)deg : 0.0f;
    float4 b = make_float4(acc.x * inv, acc.y * inv, acc.z * inv, acc.w * inv);

    // own x1 row (a) — every lane loads its float4 (groups duplicate, cached)
    float4 a = *(const float4*)&x1[(long long)node * D_FEAT + fid];

    // per-lane partials; 64-lane butterfly sums each value 4x (group dup)
    float dot = a.x * b.x + a.y * b.y + a.z * b.z + a.w * b.w;
    float nn1 = a.x * a.x + a.y * a.y + a.z * a.z + a.w * a.w;
    float nn2 = b.x * b.x + b.y * b.y + b.z * b.z + b.w * b.w;
    #pragma unroll
    for (int off = 1; off < 64; off <<= 1) {
        dot += __shfl_xor(dot, off);
        nn1 += __shfl_xor(nn1, off);
        nn2 += __shfl_xor(nn2, off);
    }
    dot *= 0.25f; nn1 *= 0.25f; nn2 *= 0.25f;

    float w = dot / fmaxf(sqrtf(nn1) * sqrtf(nn2), 1e-8f);
    if (group == 0) {
        float4 r;
        r.x = w * b.x + (1.0f - w) * a.x;
        r.y = w * b.y + (1.0f - w) * a.y;
        r.z = w * b.z + (1.0f - w) * a.z;
        r.w = w * b.w + (1.0f - w) * a.w;
        *(float4*)&out[(long long)node * D_FEAT + fid] = r;
    }
}

// ---- launch -------------------------------------------------------------

extern "C" void kernel_launch(void* const* d_in, const int* in_sizes, int n_in,
                              void* d_out, int out_size, void* d_ws, size_t ws_size,
                              hipStream_t stream) {
    const float* feat = (const float*)d_in[0];
    const int*   eidx = (const int*)d_in[1];
    const int*   src  = eidx;
    const int*   dst  = eidx + N_EDGES;

    // ws layout
    float* x1      = (float*)d_ws;                                   // 25.6 MB
    int*   counts  = (int*)(x1 + (size_t)N_NODES * D_FEAT);          // 400 KB
    int*   offsets = counts + N_NODES;                               // 400 KB (+1)
    int*   bsum    = offsets + (N_NODES + 1);                        // 512 B
    int*   csr_src = bsum + 128;                                     // 6.4 MB
    float* out     = (float*)d_out;

    hipMemsetAsync(counts, 0, N_NODES * sizeof(int), stream);

    const int BLK = 256;
    int eblocks = (N_EDGES + BLK - 1) / BLK;

    histogram_kernel<<<eblocks, BLK, 0, stream>>>(dst, counts);
    scan_block_kernel<<<N_SCAN_BLOCKS, SCAN_BLOCK, 0, stream>>>(counts, offsets, bsum);
    scan_bsum_kernel<<<1, 128, 0, stream>>>(bsum);
    scan_add_kernel<<<N_SCAN_BLOCKS, SCAN_BLOCK, 0, stream>>>(offsets, bsum, counts);
    fill_csr_kernel<<<eblocks, BLK, 0, stream>>>(src, dst, offsets, counts, csr_src);

    int nodes_per_block = BLK / 64;  // 4
    int nblocks = (N_NODES + nodes_per_block - 1) / nodes_per_block;
    gather1_kernel<<<nblocks, BLK, 0, stream>>>(feat, offsets, csr_src, x1);
    gather2_finalize_kernel<<<nblocks, BLK, 0, stream>>>(x1, offsets, csr_src, out);
}

// Round 3
// 247.052 us; speedup vs baseline: 3.5935x; 1.5607x over previous
//
#include <hip/hip_runtime.h>
#include <math.h>

#define N_NODES 100000
#define N_EDGES 1600000
#define D_FEAT  64

#define NPB     512                                // nodes per bucket (dst>>9)
#define NB      ((N_NODES + NPB - 1) / NPB)        // 196 buckets
#define F1_WGS  512                                // chunking WGs for hist/bucketize
#define CHUNK   ((N_EDGES + F1_WGS - 1) / F1_WGS)  // 3125 edges per WG
#define STAGE_CAP 16384                            // F2 LDS staging (64 KB)

// ---- CSR build: two-level counting sort, all hot atomics in LDS ---------

// Per-WG bucket histogram -> percnt[b*F1_WGS + wg]. No global atomics.
__global__ void bucket_hist(const int* __restrict__ dst,
                            int* __restrict__ percnt) {
    __shared__ int cnt[NB];
    for (int i = threadIdx.x; i < NB; i += blockDim.x) cnt[i] = 0;
    __syncthreads();
    int e0 = blockIdx.x * CHUNK;
    int e1 = min(e0 + CHUNK, N_EDGES);
    for (int e = e0 + threadIdx.x; e < e1; e += blockDim.x)
        atomicAdd(&cnt[dst[e] >> 9], 1);
    __syncthreads();
    for (int i = threadIdx.x; i < NB; i += blockDim.x)
        percnt[i * F1_WGS + blockIdx.x] = cnt[i];
}

// Per-bucket exclusive scan across the F1_WGS workgroups (in place);
// bucket totals -> bhist.
__global__ void bucket_colscan(int* __restrict__ percnt,
                               int* __restrict__ bhist) {
    __shared__ int tmp[F1_WGS];
    int b = blockIdx.x;
    int v = percnt[b * F1_WGS + threadIdx.x];
    tmp[threadIdx.x] = v;
    __syncthreads();
    for (int o = 1; o < F1_WGS; o <<= 1) {
        int t = (threadIdx.x >= o) ? tmp[threadIdx.x - o] : 0;
        __syncthreads();
        tmp[threadIdx.x] += t;
        __syncthreads();
    }
    percnt[b * F1_WGS + threadIdx.x] = tmp[threadIdx.x] - v;  // exclusive
    if (threadIdx.x == F1_WGS - 1) bhist[b] = tmp[F1_WGS - 1];
}

// Exclusive scan of NB bucket totals -> bbase[0..NB].
__global__ void bucket_scan(const int* __restrict__ bhist,
                            int* __restrict__ bbase) {
    __shared__ int tmp[256];
    int i = threadIdx.x;
    int v = (i < NB) ? bhist[i] : 0;
    tmp[i] = v;
    __syncthreads();
    for (int o = 1; o < 256; o <<= 1) {
        int t = (i >= o) ? tmp[i - o] : 0;
        __syncthreads();
        tmp[i] += t;
        __syncthreads();
    }
    if (i < NB) bbase[i] = tmp[i] - v;
    if (i == 0) bbase[NB] = N_EDGES;
}

// Scatter edges into bucket-contiguous tmp, packed (src<<9)|(dst&511).
// LDS cursors only; deterministic global bases; stores fire-and-forget.
__global__ void bucketize(const int* __restrict__ src,
                          const int* __restrict__ dst,
                          const int* __restrict__ bbase,
                          const int* __restrict__ percnt,
                          unsigned int* __restrict__ tmp) {
    __shared__ int base[NB];
    __shared__ int cur[NB];
    int wg = blockIdx.x;
    for (int i = threadIdx.x; i < NB; i += blockDim.x) {
        base[i] = bbase[i] + percnt[i * F1_WGS + wg];
        cur[i] = 0;
    }
    __syncthreads();
    int e0 = wg * CHUNK;
    int e1 = min(e0 + CHUNK, N_EDGES);
    for (int e = e0 + threadIdx.x; e < e1; e += blockDim.x) {
        int d = dst[e];
        int b = d >> 9;
        int r = atomicAdd(&cur[b], 1);
        tmp[base[b] + r] = ((unsigned)src[e] << 9) | (unsigned)(d & 511);
    }
}

// One WG per bucket: node histogram + scan in LDS -> offsets (coalesced),
// then LDS-stage the within-bucket sort -> csr_src flushed coalesced.
__global__ __launch_bounds__(NPB) void bucket_csr(
        const unsigned int* __restrict__ tmp,
        const int* __restrict__ bbase,
        int* __restrict__ offsets,
        int* __restrict__ csr_src) {
    __shared__ int cnt[NPB];
    __shared__ int off[NPB];
    __shared__ int stage[STAGE_CAP];
    int b = blockIdx.x;
    int ebase = bbase[b];
    int ecnt  = bbase[b + 1] - ebase;
    int node0 = b * NPB;
    int nodes_in = min(NPB, N_NODES - node0);

    cnt[threadIdx.x] = 0;
    __syncthreads();
    for (int i = threadIdx.x; i < ecnt; i += blockDim.x)
        atomicAdd(&cnt[tmp[ebase + i] & 511], 1);
    __syncthreads();

    // block-wide exclusive scan of cnt[0..NPB)
    int v = cnt[threadIdx.x];
    off[threadIdx.x] = v;
    __syncthreads();
    for (int o = 1; o < NPB; o <<= 1) {
        int t = (threadIdx.x >= o) ? off[threadIdx.x - o] : 0;
        __syncthreads();
        off[threadIdx.x] += t;
        __syncthreads();
    }
    int excl = off[threadIdx.x] - v;
    __syncthreads();
    off[threadIdx.x] = excl;
    cnt[threadIdx.x] = 0;  // reuse as cursor
    if (threadIdx.x < nodes_in) offsets[node0 + threadIdx.x] = ebase + excl;
    if (b == NB - 1 && threadIdx.x == 0) offsets[N_NODES] = N_EDGES;
    __syncthreads();

    if (ecnt <= STAGE_CAP) {
        for (int i = threadIdx.x; i < ecnt; i += blockDim.x) {
            unsigned u = tmp[ebase + i];
            int d = (int)(u & 511);
            int r = atomicAdd(&cnt[d], 1);
            stage[off[d] + r] = (int)(u >> 9);
        }
        __syncthreads();
        for (int i = threadIdx.x; i < ecnt; i += blockDim.x)
            csr_src[ebase + i] = stage[i];
    } else {
        // correct fallback (never hit for this dataset): direct scatter,
        // confined to a ~4*ecnt-byte region -> L2-resident
        for (int i = threadIdx.x; i < ecnt; i += blockDim.x) {
            unsigned u = tmp[ebase + i];
            int d = (int)(u & 511);
            int r = atomicAdd(&cnt[d], 1);
            csr_src[ebase + off[d] + r] = (int)(u >> 9);
        }
    }
}

// ---- Gather passes (unchanged from round 2) -----------------------------

__global__ void gather1_kernel(const float* __restrict__ feat,
                               const int* __restrict__ offsets,
                               const int* __restrict__ csr_src,
                               float* __restrict__ x1) {
    int node = blockIdx.x * (blockDim.x >> 6) + (threadIdx.x >> 6);
    if (node >= N_NODES) return;
    int lane = threadIdx.x & 63;
    int group = lane >> 4;
    int fid = (lane & 15) * 4;

    int base = offsets[node];
    int deg = offsets[node + 1] - base;

    float4 acc = make_float4(0.f, 0.f, 0.f, 0.f);
    for (int j = 0; j < deg; j += 4) {
        int idx = j + group;
        if (idx < deg) {
            int s = csr_src[base + idx];
            float4 v = *(const float4*)&feat[(long long)s * D_FEAT + fid];
            acc.x += v.x; acc.y += v.y; acc.z += v.z; acc.w += v.w;
        }
    }
    acc.x += __shfl_xor(acc.x, 16); acc.x += __shfl_xor(acc.x, 32);
    acc.y += __shfl_xor(acc.y, 16); acc.y += __shfl_xor(acc.y, 32);
    acc.z += __shfl_xor(acc.z, 16); acc.z += __shfl_xor(acc.z, 32);
    acc.w += __shfl_xor(acc.w, 16); acc.w += __shfl_xor(acc.w, 32);

    if (group == 0) {
        float inv = (deg > 0) ? 1.0f / (float)deg : 0.0f;
        float4 r = make_float4(acc.x * inv, acc.y * inv, acc.z * inv, acc.w * inv);
        *(float4*)&x1[(long long)node * D_FEAT + fid] = r;
    }
}

__global__ void gather2_finalize_kernel(const float* __restrict__ x1,
                                        const int* __restrict__ offsets,
                                        const int* __restrict__ csr_src,
                                        float* __restrict__ out) {
    int node = blockIdx.x * (blockDim.x >> 6) + (threadIdx.x >> 6);
    if (node >= N_NODES) return;
    int lane = threadIdx.x & 63;
    int group = lane >> 4;
    int fid = (lane & 15) * 4;

    int base = offsets[node];
    int deg = offsets[node + 1] - base;

    float4 acc = make_float4(0.f, 0.f, 0.f, 0.f);
    for (int j = 0; j < deg; j += 4) {
        int idx = j + group;
        if (idx < deg) {
            int s = csr_src[base + idx];
            float4 v = *(const float4*)&x1[(long long)s * D_FEAT + fid];
            acc.x += v.x; acc.y += v.y; acc.z += v.z; acc.w += v.w;
        }
    }
    acc.x += __shfl_xor(acc.x, 16); acc.x += __shfl_xor(acc.x, 32);
    acc.y += __shfl_xor(acc.y, 16); acc.y += __shfl_xor(acc.y, 32);
    acc.z += __shfl_xor(acc.z, 16); acc.z += __shfl_xor(acc.z, 32);
    acc.w += __shfl_xor(acc.w, 16); acc.w += __shfl_xor(acc.w, 32);

    float inv = (deg > 0) ? 1.0f / (float)deg : 0.0f;
    float4 bb = make_float4(acc.x * inv, acc.y * inv, acc.z * inv, acc.w * inv);

    float4 a = *(const float4*)&x1[(long long)node * D_FEAT + fid];

    float dot = a.x * bb.x + a.y * bb.y + a.z * bb.z + a.w * bb.w;
    float nn1 = a.x * a.x + a.y * a.y + a.z * a.z + a.w * a.w;
    float nn2 = bb.x * bb.x + bb.y * bb.y + bb.z * bb.z + bb.w * bb.w;
    #pragma unroll
    for (int off = 1; off < 64; off <<= 1) {
        dot += __shfl_xor(dot, off);
        nn1 += __shfl_xor(nn1, off);
        nn2 += __shfl_xor(nn2, off);
    }
    dot *= 0.25f; nn1 *= 0.25f; nn2 *= 0.25f;

    float w = dot / fmaxf(sqrtf(nn1) * sqrtf(nn2), 1e-8f);
    if (group == 0) {
        float4 r;
        r.x = w * bb.x + (1.0f - w) * a.x;
        r.y = w * bb.y + (1.0f - w) * a.y;
        r.z = w * bb.z + (1.0f - w) * a.z;
        r.w = w * bb.w + (1.0f - w) * a.w;
        *(float4*)&out[(long long)node * D_FEAT + fid] = r;
    }
}

// ---- launch -------------------------------------------------------------

extern "C" void kernel_launch(void* const* d_in, const int* in_sizes, int n_in,
                              void* d_out, int out_size, void* d_ws, size_t ws_size,
                              hipStream_t stream) {
    const float* feat = (const float*)d_in[0];
    const int*   eidx = (const int*)d_in[1];
    const int*   src  = eidx;
    const int*   dst  = eidx + N_EDGES;

    float*        x1      = (float*)d_ws;                         // 25.6 MB
    int*          offsets = (int*)(x1 + (size_t)N_NODES * D_FEAT);// 100001
    int*          percnt  = offsets + (N_NODES + 1);              // NB*F1_WGS
    int*          bhist   = percnt + NB * F1_WGS;                 // NB
    int*          bbase   = bhist + NB;                           // NB+1
    unsigned int* tmp     = (unsigned int*)(bbase + (NB + 1));    // 6.4 MB
    int*          csr_src = (int*)(tmp + N_EDGES);                // 6.4 MB
    float*        out     = (float*)d_out;

    bucket_hist   <<<F1_WGS, 256, 0, stream>>>(dst, percnt);
    bucket_colscan<<<NB, F1_WGS, 0, stream>>>(percnt, bhist);
    bucket_scan   <<<1, 256, 0, stream>>>(bhist, bbase);
    bucketize     <<<F1_WGS, 256, 0, stream>>>(src, dst, bbase, percnt, tmp);
    bucket_csr    <<<NB, NPB, 0, stream>>>(tmp, bbase, offsets, csr_src);

    const int BLK = 256;
    int nodes_per_block = BLK / 64;  // 4
    int nblocks = (N_NODES + nodes_per_block - 1) / nodes_per_block;
    gather1_kernel<<<nblocks, BLK, 0, stream>>>(feat, offsets, csr_src, x1);
    gather2_finalize_kernel<<<nblocks, BLK, 0, stream>>>(x1, offsets, csr_src, out);
}

// Round 4
// 211.626 us; speedup vs baseline: 4.1950x; 1.1674x over previous
//
#include <hip/hip_runtime.h>
#include <hip/hip_fp16.h>
#include <math.h>

#define N_NODES 100000
#define N_EDGES 1600000
#define D_FEAT  64

#define NPB     512                                // nodes per bucket (dst>>9)
#define NB      ((N_NODES + NPB - 1) / NPB)        // 196 buckets
#define F1_WGS  512                                // chunking WGs for hist/bucketize
#define CHUNK   ((N_EDGES + F1_WGS - 1) / F1_WGS)  // 3125 edges per WG
#define STAGE_CAP 16384                            // F2 LDS staging (64 KB)

// ---- CSR build: two-level counting sort, all hot atomics in LDS ---------

__global__ void bucket_hist(const int* __restrict__ dst,
                            int* __restrict__ percnt) {
    __shared__ int cnt[NB];
    for (int i = threadIdx.x; i < NB; i += blockDim.x) cnt[i] = 0;
    __syncthreads();
    int e0 = blockIdx.x * CHUNK;
    int e1 = min(e0 + CHUNK, N_EDGES);
    for (int e = e0 + threadIdx.x; e < e1; e += blockDim.x)
        atomicAdd(&cnt[dst[e] >> 9], 1);
    __syncthreads();
    for (int i = threadIdx.x; i < NB; i += blockDim.x)
        percnt[i * F1_WGS + blockIdx.x] = cnt[i];
}

__global__ void bucket_colscan(int* __restrict__ percnt,
                               int* __restrict__ bhist) {
    __shared__ int tmp[F1_WGS];
    int b = blockIdx.x;
    int v = percnt[b * F1_WGS + threadIdx.x];
    tmp[threadIdx.x] = v;
    __syncthreads();
    for (int o = 1; o < F1_WGS; o <<= 1) {
        int t = (threadIdx.x >= o) ? tmp[threadIdx.x - o] : 0;
        __syncthreads();
        tmp[threadIdx.x] += t;
        __syncthreads();
    }
    percnt[b * F1_WGS + threadIdx.x] = tmp[threadIdx.x] - v;  // exclusive
    if (threadIdx.x == F1_WGS - 1) bhist[b] = tmp[F1_WGS - 1];
}

__global__ void bucket_scan(const int* __restrict__ bhist,
                            int* __restrict__ bbase) {
    __shared__ int tmp[256];
    int i = threadIdx.x;
    int v = (i < NB) ? bhist[i] : 0;
    tmp[i] = v;
    __syncthreads();
    for (int o = 1; o < 256; o <<= 1) {
        int t = (i >= o) ? tmp[i - o] : 0;
        __syncthreads();
        tmp[i] += t;
        __syncthreads();
    }
    if (i < NB) bbase[i] = tmp[i] - v;
    if (i == 0) bbase[NB] = N_EDGES;
}

__global__ void bucketize(const int* __restrict__ src,
                          const int* __restrict__ dst,
                          const int* __restrict__ bbase,
                          const int* __restrict__ percnt,
                          unsigned int* __restrict__ tmp) {
    __shared__ int base[NB];
    __shared__ int cur[NB];
    int wg = blockIdx.x;
    for (int i = threadIdx.x; i < NB; i += blockDim.x) {
        base[i] = bbase[i] + percnt[i * F1_WGS + wg];
        cur[i] = 0;
    }
    __syncthreads();
    int e0 = wg * CHUNK;
    int e1 = min(e0 + CHUNK, N_EDGES);
    for (int e = e0 + threadIdx.x; e < e1; e += blockDim.x) {
        int d = dst[e];
        int b = d >> 9;
        int r = atomicAdd(&cur[b], 1);
        tmp[base[b] + r] = ((unsigned)src[e] << 9) | (unsigned)(d & 511);
    }
}

__global__ __launch_bounds__(NPB) void bucket_csr(
        const unsigned int* __restrict__ tmp,
        const int* __restrict__ bbase,
        int* __restrict__ offsets,
        int* __restrict__ csr_src) {
    __shared__ int cnt[NPB];
    __shared__ int off[NPB];
    __shared__ int stage[STAGE_CAP];
    int b = blockIdx.x;
    int ebase = bbase[b];
    int ecnt  = bbase[b + 1] - ebase;
    int node0 = b * NPB;
    int nodes_in = min(NPB, N_NODES - node0);

    cnt[threadIdx.x] = 0;
    __syncthreads();
    for (int i = threadIdx.x; i < ecnt; i += blockDim.x)
        atomicAdd(&cnt[tmp[ebase + i] & 511], 1);
    __syncthreads();

    int v = cnt[threadIdx.x];
    off[threadIdx.x] = v;
    __syncthreads();
    for (int o = 1; o < NPB; o <<= 1) {
        int t = (threadIdx.x >= o) ? off[threadIdx.x - o] : 0;
        __syncthreads();
        off[threadIdx.x] += t;
        __syncthreads();
    }
    int excl = off[threadIdx.x] - v;
    __syncthreads();
    off[threadIdx.x] = excl;
    cnt[threadIdx.x] = 0;  // reuse as cursor
    if (threadIdx.x < nodes_in) offsets[node0 + threadIdx.x] = ebase + excl;
    if (b == NB - 1 && threadIdx.x == 0) offsets[N_NODES] = N_EDGES;
    __syncthreads();

    if (ecnt <= STAGE_CAP) {
        for (int i = threadIdx.x; i < ecnt; i += blockDim.x) {
            unsigned u = tmp[ebase + i];
            int d = (int)(u & 511);
            int r = atomicAdd(&cnt[d], 1);
            stage[off[d] + r] = (int)(u >> 9);
        }
        __syncthreads();
        for (int i = threadIdx.x; i < ecnt; i += blockDim.x)
            csr_src[ebase + i] = stage[i];
    } else {
        for (int i = threadIdx.x; i < ecnt; i += blockDim.x) {
            unsigned u = tmp[ebase + i];
            int d = (int)(u & 511);
            int r = atomicAdd(&cnt[d], 1);
            csr_src[ebase + off[d] + r] = (int)(u >> 9);
        }
    }
}

// ---- fp16 cast of the feature table -------------------------------------

__global__ void cast_feat(const float* __restrict__ in,
                          __half* __restrict__ out) {
    int i = blockIdx.x * blockDim.x + threadIdx.x;   // one per 4 elems
    if (i >= (N_NODES * D_FEAT) / 4) return;
    float4 v = ((const float4*)in)[i];
    __half2 h0 = __floats2half2_rn(v.x, v.y);
    __half2 h1 = __floats2half2_rn(v.z, v.w);
    uint2 st;
    st.x = *(unsigned*)&h0;
    st.y = *(unsigned*)&h1;
    ((uint2*)out)[i] = st;
}

// ---- Gather passes (fp16 rows: 128B/row, 8 lanes/row, 8 edges/wave-iter) -

__global__ void gather1_kernel(const __half* __restrict__ feat_h,
                               const int* __restrict__ offsets,
                               const int* __restrict__ csr_src,
                               __half* __restrict__ x1_h) {
    int node = blockIdx.x * (blockDim.x >> 6) + (threadIdx.x >> 6);
    if (node >= N_NODES) return;
    int lane = threadIdx.x & 63;
    int g = lane >> 3;            // edge sub-batch 0..7
    int fid = (lane & 7) * 8;     // 8 feats per lane

    int base = offsets[node];
    int deg = offsets[node + 1] - base;

    float acc[8] = {0.f,0.f,0.f,0.f,0.f,0.f,0.f,0.f};
    for (int j = g; j < deg; j += 8) {
        int s = csr_src[base + j];
        uint4 u = *(const uint4*)(feat_h + (size_t)s * D_FEAT + fid);
        { __half2 h = *(__half2*)&u.x; float2 f = __half22float2(h); acc[0]+=f.x; acc[1]+=f.y; }
        { __half2 h = *(__half2*)&u.y; float2 f = __half22float2(h); acc[2]+=f.x; acc[3]+=f.y; }
        { __half2 h = *(__half2*)&u.z; float2 f = __half22float2(h); acc[4]+=f.x; acc[5]+=f.y; }
        { __half2 h = *(__half2*)&u.w; float2 f = __half22float2(h); acc[6]+=f.x; acc[7]+=f.y; }
    }
    #pragma unroll
    for (int m = 8; m < 64; m <<= 1)
        #pragma unroll
        for (int t = 0; t < 8; t++)
            acc[t] += __shfl_xor(acc[t], m);

    if (lane < 8) {
        float inv = (deg > 0) ? 1.0f / (float)deg : 0.0f;
        __half2 h0 = __floats2half2_rn(acc[0]*inv, acc[1]*inv);
        __half2 h1 = __floats2half2_rn(acc[2]*inv, acc[3]*inv);
        __half2 h2 = __floats2half2_rn(acc[4]*inv, acc[5]*inv);
        __half2 h3 = __floats2half2_rn(acc[6]*inv, acc[7]*inv);
        uint4 st;
        st.x = *(unsigned*)&h0; st.y = *(unsigned*)&h1;
        st.z = *(unsigned*)&h2; st.w = *(unsigned*)&h3;
        *(uint4*)(x1_h + (size_t)node * D_FEAT + fid) = st;
    }
}

__global__ void gather2_finalize_kernel(const __half* __restrict__ x1_h,
                                        const int* __restrict__ offsets,
                                        const int* __restrict__ csr_src,
                                        float* __restrict__ out) {
    int node = blockIdx.x * (blockDim.x >> 6) + (threadIdx.x >> 6);
    if (node >= N_NODES) return;
    int lane = threadIdx.x & 63;
    int g = lane >> 3;
    int fid = (lane & 7) * 8;

    int base = offsets[node];
    int deg = offsets[node + 1] - base;

    float acc[8] = {0.f,0.f,0.f,0.f,0.f,0.f,0.f,0.f};
    for (int j = g; j < deg; j += 8) {
        int s = csr_src[base + j];
        uint4 u = *(const uint4*)(x1_h + (size_t)s * D_FEAT + fid);
        { __half2 h = *(__half2*)&u.x; float2 f = __half22float2(h); acc[0]+=f.x; acc[1]+=f.y; }
        { __half2 h = *(__half2*)&u.y; float2 f = __half22float2(h); acc[2]+=f.x; acc[3]+=f.y; }
        { __half2 h = *(__half2*)&u.z; float2 f = __half22float2(h); acc[4]+=f.x; acc[5]+=f.y; }
        { __half2 h = *(__half2*)&u.w; float2 f = __half22float2(h); acc[6]+=f.x; acc[7]+=f.y; }
    }
    #pragma unroll
    for (int m = 8; m < 64; m <<= 1)
        #pragma unroll
        for (int t = 0; t < 8; t++)
            acc[t] += __shfl_xor(acc[t], m);

    float inv = (deg > 0) ? 1.0f / (float)deg : 0.0f;
    float b[8], a[8];
    #pragma unroll
    for (int t = 0; t < 8; t++) b[t] = acc[t] * inv;

    {   // own x1 row slice (groups duplicate; served from cache)
        uint4 u = *(const uint4*)(x1_h + (size_t)node * D_FEAT + fid);
        { __half2 h = *(__half2*)&u.x; float2 f = __half22float2(h); a[0]=f.x; a[1]=f.y; }
        { __half2 h = *(__half2*)&u.y; float2 f = __half22float2(h); a[2]=f.x; a[3]=f.y; }
        { __half2 h = *(__half2*)&u.z; float2 f = __half22float2(h); a[4]=f.x; a[5]=f.y; }
        { __half2 h = *(__half2*)&u.w; float2 f = __half22float2(h); a[6]=f.x; a[7]=f.y; }
    }

    float dot = 0.f, nn1 = 0.f, nn2 = 0.f;
    #pragma unroll
    for (int t = 0; t < 8; t++) {
        dot += a[t] * b[t];
        nn1 += a[t] * a[t];
        nn2 += b[t] * b[t];
    }
    #pragma unroll
    for (int m = 1; m < 64; m <<= 1) {
        dot += __shfl_xor(dot, m);
        nn1 += __shfl_xor(nn1, m);
        nn2 += __shfl_xor(nn2, m);
    }
    dot *= 0.125f; nn1 *= 0.125f; nn2 *= 0.125f;  // 8 groups duplicate

    float w = dot / fmaxf(sqrtf(nn1) * sqrtf(nn2), 1e-8f);
    if (lane < 8) {
        float4 r0, r1;
        r0.x = w*b[0] + (1.f-w)*a[0]; r0.y = w*b[1] + (1.f-w)*a[1];
        r0.z = w*b[2] + (1.f-w)*a[2]; r0.w = w*b[3] + (1.f-w)*a[3];
        r1.x = w*b[4] + (1.f-w)*a[4]; r1.y = w*b[5] + (1.f-w)*a[5];
        r1.z = w*b[6] + (1.f-w)*a[6]; r1.w = w*b[7] + (1.f-w)*a[7];
        *(float4*)(out + (size_t)node * D_FEAT + fid)     = r0;
        *(float4*)(out + (size_t)node * D_FEAT + fid + 4) = r1;
    }
}

// ---- launch -------------------------------------------------------------

extern "C" void kernel_launch(void* const* d_in, const int* in_sizes, int n_in,
                              void* d_out, int out_size, void* d_ws, size_t ws_size,
                              hipStream_t stream) {
    const float* feat = (const float*)d_in[0];
    const int*   eidx = (const int*)d_in[1];
    const int*   src  = eidx;
    const int*   dst  = eidx + N_EDGES;

    __half*       feat_h  = (__half*)d_ws;                          // 12.8 MB
    __half*       x1_h    = feat_h + (size_t)N_NODES * D_FEAT;      // 12.8 MB
    int*          offsets = (int*)(x1_h + (size_t)N_NODES * D_FEAT);// 100001
    int*          percnt  = offsets + (N_NODES + 1);                // NB*F1_WGS
    int*          bhist   = percnt + NB * F1_WGS;                   // NB
    int*          bbase   = bhist + NB;                             // NB+1
    unsigned int* tmp     = (unsigned int*)(bbase + (NB + 1));      // 6.4 MB
    int*          csr_src = (int*)(tmp + N_EDGES);                  // 6.4 MB
    float*        out     = (float*)d_out;

    const int BLK = 256;
    int castn = (N_NODES * D_FEAT) / 4;
    cast_feat<<<(castn + BLK - 1) / BLK, BLK, 0, stream>>>(feat, feat_h);

    bucket_hist   <<<F1_WGS, 256, 0, stream>>>(dst, percnt);
    bucket_colscan<<<NB, F1_WGS, 0, stream>>>(percnt, bhist);
    bucket_scan   <<<1, 256, 0, stream>>>(bhist, bbase);
    bucketize     <<<F1_WGS, 256, 0, stream>>>(src, dst, bbase, percnt, tmp);
    bucket_csr    <<<NB, NPB, 0, stream>>>(tmp, bbase, offsets, csr_src);

    int nodes_per_block = BLK / 64;  // 4
    int nblocks = (N_NODES + nodes_per_block - 1) / nodes_per_block;
    gather1_kernel<<<nblocks, BLK, 0, stream>>>(feat_h, offsets, csr_src, x1_h);
    gather2_finalize_kernel<<<nblocks, BLK, 0, stream>>>(x1_h, offsets, csr_src, out);
}